// Round 1
// baseline (325.073 us; speedup 1.0000x reference)
//
#include <hip/hip_runtime.h>
#include <stdint.h>

#define N_ITEMS   200000
#define N_USERS   16384
#define N_HIST    819200

typedef short bfrag8 __attribute__((ext_vector_type(8)));
typedef float ffrag4 __attribute__((ext_vector_type(4)));

__device__ __forceinline__ unsigned short f2bf(float f) {
    union { float f; unsigned int u; } v; v.f = f;
    unsigned int u = v.u;
    u += 0x7fffu + ((u >> 16) & 1u);   // round-to-nearest-even
    return (unsigned short)(u >> 16);
}

__device__ __forceinline__ ffrag4 mfma16(bfrag8 a, bfrag8 b, ffrag4 c) {
    return __builtin_amdgcn_mfma_f32_16x16x32_bf16(a, b, c, 0, 0, 0);
}

// ---------------------------------------------------------------------------
// K0: transpose + convert weights to bf16.  out[n*K+k] = bf16(w[k*N+n])
// ---------------------------------------------------------------------------
__global__ void cvtT_kernel(const float* __restrict__ w, unsigned short* __restrict__ o,
                            int K, int N) {
    int id = blockIdx.x * 256 + threadIdx.x;
    if (id >= K * N) return;
    int n = id / K;
    int k = id - n * K;
    o[id] = f2bf(w[(size_t)k * N + n]);
}

// ---------------------------------------------------------------------------
// K1/K3: fused two-layer MLP tower + L2 normalize.
//   x = [srcA_row || srcB_row]  (128 + 128)
//   h = relu(x @ W1 + b1)   (256)
//   y = h @ W2 + b2         (128);  out = y / max(||y||, 1e-12)
// srcA row index = rowIdxA ? rowIdxA[row] : row ; srcB row index = row.
// Weights pre-transposed bf16: w1t[n][k] (256x256), w2t[n][k] (128x256).
// Block: 256 threads (4 waves), BM=64 rows, wave w owns rows [16w,16w+16).
// ---------------------------------------------------------------------------
#define BM 64
#define A_STRIDE 528                 // 512 data bytes + 16 pad (bank spread)
#define W_STRIDE 80                  // 64 data bytes + 16 pad
#define A_BYTES  (BM * A_STRIDE)     // 33792
#define W_BYTES  (256 * W_STRIDE)    // 20480

__global__ __launch_bounds__(256) void tower_kernel(
    const float* __restrict__ srcA, const float* __restrict__ srcB,
    const int* __restrict__ rowIdxA,
    const unsigned short* __restrict__ w1t, const float* __restrict__ b1,
    const unsigned short* __restrict__ w2t, const float* __restrict__ b2,
    float* __restrict__ out)
{
    __shared__ __align__(16) char smem[A_BYTES + W_BYTES];
    char* smemA = smem;
    char* smemW = smem + A_BYTES;

    const int rowsBase = blockIdx.x * BM;
    const int lane = threadIdx.x & 63;
    const int wave = threadIdx.x >> 6;
    const int lr = lane & 15;        // row-in-tile (A) / col (B,C)
    const int lg = lane >> 4;        // k-group
    const int R0 = wave * 16;        // wave's row-tile base within block

    // ---- stage A tile: 64 rows x 256 cols fp32 -> bf16 LDS -----------------
    // chunk c: row = c>>5, cb = c&31 ; cb<16 -> srcA cols cb*8, else srcB.
    for (int i = 0; i < 8; ++i) {
        int c  = threadIdx.x + 256 * i;
        int r  = c >> 5;
        int cb = c & 31;
        int gr = rowsBase + r;
        const float* src;
        if (cb < 16) {
            int sr = rowIdxA ? rowIdxA[gr] : gr;
            src = srcA + (size_t)sr * 128 + cb * 8;
        } else {
            src = srcB + (size_t)gr * 128 + (cb - 16) * 8;
        }
        float4 x0 = ((const float4*)src)[0];
        float4 x1 = ((const float4*)src)[1];
        uint4 w;
        w.x = (unsigned)f2bf(x0.x) | ((unsigned)f2bf(x0.y) << 16);
        w.y = (unsigned)f2bf(x0.z) | ((unsigned)f2bf(x0.w) << 16);
        w.z = (unsigned)f2bf(x1.x) | ((unsigned)f2bf(x1.y) << 16);
        w.w = (unsigned)f2bf(x1.z) | ((unsigned)f2bf(x1.w) << 16);
        *(uint4*)(smemA + r * A_STRIDE + cb * 16) = w;
    }

    // ---- GEMM1: h[64x256] = A[64x256] @ W1[256x256] ------------------------
    ffrag4 acc[16];
#pragma unroll
    for (int i = 0; i < 16; ++i) acc[i] = (ffrag4){0.f, 0.f, 0.f, 0.f};

    for (int kt = 0; kt < 8; ++kt) {
        __syncthreads();   // previous slab consumed (and A staged, first iter)
        {   // stage W1 slab: rows n=0..255, k-bytes [kt*64, kt*64+64)
            int n = threadIdx.x;
            const uint4* g = (const uint4*)((const char*)w1t + (size_t)n * 512 + kt * 64);
            uint4* d = (uint4*)(smemW + n * W_STRIDE);
            d[0] = g[0]; d[1] = g[1]; d[2] = g[2]; d[3] = g[3];
        }
        __syncthreads();
        bfrag8 a = *(const bfrag8*)(smemA + (R0 + lr) * A_STRIDE + kt * 64 + lg * 16);
#pragma unroll
        for (int nt = 0; nt < 16; ++nt) {
            bfrag8 b = *(const bfrag8*)(smemW + (nt * 16 + lr) * W_STRIDE + lg * 16);
            acc[nt] = mfma16(a, b, acc[nt]);
        }
    }

    // ---- epilogue1: +bias, relu, bf16 -> LDS h (reuse A tile, own rows) ----
#pragma unroll
    for (int nt = 0; nt < 16; ++nt) {
        int col = nt * 16 + lr;
        float bias = b1[col];
#pragma unroll
        for (int r = 0; r < 4; ++r) {
            float v = acc[nt][r] + bias;
            v = fmaxf(v, 0.f);
            int row = R0 + lg * 4 + r;
            *(unsigned short*)(smemA + row * A_STRIDE + col * 2) = f2bf(v);
        }
    }

    // ---- GEMM2: y[64x128] = h[64x256] @ W2[256x128] ------------------------
    ffrag4 acc2[8];
#pragma unroll
    for (int i = 0; i < 8; ++i) acc2[i] = (ffrag4){0.f, 0.f, 0.f, 0.f};

    for (int kt = 0; kt < 8; ++kt) {
        __syncthreads();
        if (threadIdx.x < 128) {    // stage W2 slab: rows n=0..127
            int n = threadIdx.x;
            const uint4* g = (const uint4*)((const char*)w2t + (size_t)n * 512 + kt * 64);
            uint4* d = (uint4*)(smemW + n * W_STRIDE);
            d[0] = g[0]; d[1] = g[1]; d[2] = g[2]; d[3] = g[3];
        }
        __syncthreads();
        bfrag8 a = *(const bfrag8*)(smemA + (R0 + lr) * A_STRIDE + kt * 64 + lg * 16);
#pragma unroll
        for (int nt = 0; nt < 8; ++nt) {
            bfrag8 b = *(const bfrag8*)(smemW + (nt * 16 + lr) * W_STRIDE + lg * 16);
            acc2[nt] = mfma16(a, b, acc2[nt]);
        }
    }

    // ---- epilogue2: +bias, row L2-norm across 16-lane group, store ---------
    float y[8][4];
    float p0 = 0.f, p1 = 0.f, p2 = 0.f, p3 = 0.f;
#pragma unroll
    for (int nt = 0; nt < 8; ++nt) {
        int col = nt * 16 + lr;
        float bias = b2[col];
        float v;
        v = acc2[nt][0] + bias; y[nt][0] = v; p0 += v * v;
        v = acc2[nt][1] + bias; y[nt][1] = v; p1 += v * v;
        v = acc2[nt][2] + bias; y[nt][2] = v; p2 += v * v;
        v = acc2[nt][3] + bias; y[nt][3] = v; p3 += v * v;
    }
#pragma unroll
    for (int off = 8; off >= 1; off >>= 1) {
        p0 += __shfl_xor(p0, off, 16);
        p1 += __shfl_xor(p1, off, 16);
        p2 += __shfl_xor(p2, off, 16);
        p3 += __shfl_xor(p3, off, 16);
    }
    float s0 = 1.f / fmaxf(sqrtf(p0), 1e-12f);
    float s1 = 1.f / fmaxf(sqrtf(p1), 1e-12f);
    float s2 = 1.f / fmaxf(sqrtf(p2), 1e-12f);
    float s3 = 1.f / fmaxf(sqrtf(p3), 1e-12f);
#pragma unroll
    for (int nt = 0; nt < 8; ++nt) {
        int col = nt * 16 + lr;
        size_t rb = (size_t)(rowsBase + R0 + lg * 4) * 128 + col;
        out[rb + 0 * 128] = y[nt][0] * s0;
        out[rb + 1 * 128] = y[nt][1] * s1;
        out[rb + 2 * 128] = y[nt][2] * s2;
        out[rb + 3 * 128] = y[nt][3] * s3;
    }
}

// ---------------------------------------------------------------------------
// K2: per-user segment mean over sorted hist.  1 wave per user.
// ---------------------------------------------------------------------------
__global__ __launch_bounds__(64) void pool_kernel(
    const float* __restrict__ itemEmb,
    const int* __restrict__ histItems,
    const int* __restrict__ histSeg,
    float* __restrict__ hist)
{
    const int u = blockIdx.x;
    const int lane = threadIdx.x;

    int lo = 0, hi = N_HIST;
    while (lo < hi) { int m = (lo + hi) >> 1; if (histSeg[m] < u) lo = m + 1; else hi = m; }
    const int s = lo;
    hi = N_HIST;
    while (lo < hi) { int m = (lo + hi) >> 1; if (histSeg[m] < u + 1) lo = m + 1; else hi = m; }
    const int e = lo;

    float ax = 0.f, ay = 0.f;
    for (int i = s; i < e; ++i) {
        int idx = histItems[i];
        float2 v = *(const float2*)(itemEmb + (size_t)idx * 128 + lane * 2);
        ax += v.x; ay += v.y;
    }
    int cnt = e - s;
    float inv = (cnt > 0) ? 1.f / (float)cnt : 0.f;
    float2 r; r.x = ax * inv; r.y = ay * inv;
    *(float2*)(hist + (size_t)u * 128 + lane * 2) = r;
}

// ---------------------------------------------------------------------------
extern "C" void kernel_launch(void* const* d_in, const int* in_sizes, int n_in,
                              void* d_out, int out_size, void* d_ws, size_t ws_size,
                              hipStream_t stream) {
    const float* text    = (const float*)d_in[0];
    const float* gcnItem = (const float*)d_in[1];
    const float* gcnUser = (const float*)d_in[2];
    const float* w1i = (const float*)d_in[3];
    const float* b1i = (const float*)d_in[4];
    const float* w2i = (const float*)d_in[5];
    const float* b2i = (const float*)d_in[6];
    const float* w1u = (const float*)d_in[7];
    const float* b1u = (const float*)d_in[8];
    const float* w2u = (const float*)d_in[9];
    const float* b2u = (const float*)d_in[10];
    const int* users     = (const int*)d_in[11];
    const int* histItems = (const int*)d_in[12];
    const int* histSeg   = (const int*)d_in[13];

    float* outUser = (float*)d_out;                          // [16384][128]
    float* outItem = (float*)d_out + (size_t)N_USERS * 128;  // [200000][128]

    char* ws = (char*)d_ws;
    unsigned short* w1ti = (unsigned short*)(ws + 0);        // 256*256 bf16
    unsigned short* w2ti = (unsigned short*)(ws + 131072);   // 128*256 bf16
    unsigned short* w1tu = (unsigned short*)(ws + 196608);
    unsigned short* w2tu = (unsigned short*)(ws + 327680);
    float*          hist = (float*)(ws + 393216);            // [16384][128] f32

    cvtT_kernel<<<256, 256, 0, stream>>>(w1i, w1ti, 256, 256);
    cvtT_kernel<<<128, 256, 0, stream>>>(w2i, w2ti, 256, 128);
    cvtT_kernel<<<256, 256, 0, stream>>>(w1u, w1tu, 256, 256);
    cvtT_kernel<<<128, 256, 0, stream>>>(w2u, w2tu, 256, 128);

    tower_kernel<<<N_ITEMS / BM, 256, 0, stream>>>(
        text, gcnItem, nullptr, w1ti, b1i, w2ti, b2i, outItem);

    pool_kernel<<<N_USERS, 64, 0, stream>>>(outItem, histItems, histSeg, hist);

    tower_kernel<<<N_USERS / BM, 256, 0, stream>>>(
        gcnUser, hist, users, w1tu, b1u, w2tu, b2u, outUser);
}